// Round 1
// baseline (49.123 us; speedup 1.0000x reference)
//
#include <hip/hip_runtime.h>
#include <math.h>

#define S_GRID   112
#define BATCH_N  64
#define NBOX     100
#define NCELLS   (BATCH_N * S_GRID * S_GRID)   // 802816
#define CELLSZ   (1.0f / (float)S_GRID)
#define BLK      256
#define NBLK2    (NCELLS / BLK)                // 3136 exactly

// ---------- device helpers ----------

__device__ __forceinline__ float iou_fn(float px, float py, float pw, float ph,
                                        float gx, float gy, float gw, float gh) {
    // matches reference _iou (eps = 1e-6)
    float px1 = px - pw * 0.5f, px2 = px + pw * 0.5f;
    float py1 = py - ph * 0.5f, py2 = py + ph * 0.5f;
    float gx1 = gx - gw * 0.5f, gx2 = gx + gw * 0.5f;
    float gy1 = gy - gh * 0.5f, gy2 = gy + gh * 0.5f;
    float iw = fmaxf(fminf(px2, gx2) - fmaxf(px1, gx1), 0.f);
    float ih = fmaxf(fminf(py2, gy2) - fmaxf(py1, gy1), 0.f);
    float inter = iw * ih;
    float ap = fmaxf(px2 - px1, 0.f) * fmaxf(py2 - py1, 0.f);
    float ag = fmaxf(gx2 - gx1, 0.f) * fmaxf(gy2 - gy1, 0.f);
    float uni = ap + ag - inter;
    return inter / (uni + 1e-6f);
}

__device__ __forceinline__ float ciou_fn(float px, float py, float pw, float ph,
                                         float gx, float gy, float gw, float gh) {
    // matches reference _ciou (eps = 1e-7)
    const float eps = 1e-7f;
    float px1 = px - pw * 0.5f, px2 = px + pw * 0.5f;
    float py1 = py - ph * 0.5f, py2 = py + ph * 0.5f;
    float gx1 = gx - gw * 0.5f, gx2 = gx + gw * 0.5f;
    float gy1 = gy - gh * 0.5f, gy2 = gy + gh * 0.5f;
    float iw = fmaxf(fminf(px2, gx2) - fmaxf(px1, gx1), 0.f);
    float ih = fmaxf(fminf(py2, gy2) - fmaxf(py1, gy1), 0.f);
    float inter = iw * ih;
    float ap = fmaxf(px2 - px1, 0.f) * fmaxf(py2 - py1, 0.f);
    float ag = fmaxf(gx2 - gx1, 0.f) * fmaxf(gy2 - gy1, 0.f);
    float uni = ap + ag - inter;
    float iou = inter / (uni + eps);
    float dx = px - gx, dy = py - gy;
    float rho2 = dx * dx + dy * dy;
    float cw = fmaxf(px2, gx2) - fminf(px1, gx1);
    float ch = fmaxf(py2, gy2) - fminf(py1, gy1);
    float c2 = cw * cw + ch * ch + eps;
    float dv = atanf(gw / (gh + eps)) - atanf(pw / (ph + eps));
    float v = 0.40528473456935109f * dv * dv;   // 4/pi^2
    float alpha = v / (1.f - iou + v + eps);    // stop_gradient irrelevant (fwd only)
    return 1.f - iou + rho2 / c2 + alpha * v;
}

__device__ __forceinline__ float focal_fn(float logit, float t) {
    float bce = fmaxf(logit, 0.f) - logit * t + log1pf(expf(-fabsf(logit)));
    float p = 1.f / (1.f + expf(-logit));
    float p_t = t * p + (1.f - t) * (1.f - p);
    float a_t = t * 0.25f + (1.f - t) * 0.75f;
    float om = 1.f - p_t;
    return a_t * om * om * bce;
}

// ---------- kernel 1: per-box assignment via atomics ----------

__global__ void assign_kernel(const float* __restrict__ pred,
                              const float* __restrict__ tgt,
                              unsigned long long* __restrict__ keybuf,
                              unsigned int* __restrict__ clsmask) {
    int m = blockIdx.x * blockDim.x + threadIdx.x;
    if (m >= BATCH_N * NBOX) return;
    const float* t = tgt + (size_t)m * 5;
    float t0 = t[0];
    if (t0 < 0.f) return;                       // invalid box
    int cls = (int)t0; cls = min(max(cls, 0), 9);
    float cx = t[1], cy = t[2], gw = t[3], gh = t[4];
    int b = m / NBOX;
    int col = min(max((int)(cx * (float)S_GRID), 0), S_GRID - 1);
    int row = min(max((int)(cy * (float)S_GRID), 0), S_GRID - 1);
    const float* p = pred + ((((size_t)b * S_GRID + row) * S_GRID) + col) * 20;
    float dx0 = (p[0] + (float)col) * CELLSZ, dy0 = (p[1] + (float)row) * CELLSZ;
    float iou0 = iou_fn(dx0, dy0, p[2], p[3], cx, cy, gw, gh);
    float dx1 = (p[5] + (float)col) * CELLSZ, dy1 = (p[6] + (float)row) * CELLSZ;
    float iou1 = iou_fn(dx1, dy1, p[7], p[8], cx, cy, gw, gh);
    float best = fmaxf(iou0, iou1);             // iou >= 0 -> bits monotone as uint
    int cid = ((b * S_GRID) + row) * S_GRID + col;
    unsigned long long key =
        ((unsigned long long)__float_as_uint(best) << 32) |
        (unsigned long long)(0xFFFFFFFFu - (unsigned)m);   // tie-break: smallest m wins
    atomicMax(&keybuf[cid], key);
    atomicOr(&clsmask[cid], 1u << cls);
}

// ---------- kernel 2: per-cell loss ----------

__global__ void loss_kernel(const float* __restrict__ pred,
                            const float* __restrict__ tgt,
                            const unsigned long long* __restrict__ keybuf,
                            const unsigned int* __restrict__ clsmask,
                            float* __restrict__ partial) {
    int cid = blockIdx.x * blockDim.x + threadIdx.x;   // grid covers NCELLS exactly
    float acc = 0.f;

    const float4* p4 = (const float4*)(pred + (size_t)cid * 20);
    float4 a = p4[0];   // px0 py0 pw0 ph0
    float4 bq = p4[1];  // conf0 px1 py1 pw1
    float4 c = p4[2];   // ph1 conf1 cls0 cls1
    float4 d = p4[3];   // cls2..cls5
    float4 e = p4[4];   // cls6..cls9
    float conf0 = bq.x, conf1 = c.y;

    unsigned int mask = clsmask[cid];
    if (mask == 0u) {
        // no-object cell: both boxes' confidence penalized
        acc = 0.1f * (conf0 * conf0 + conf1 * conf1);
    } else {
        int rc  = cid % (S_GRID * S_GRID);
        float colf = (float)(rc % S_GRID);
        float rowf = (float)(rc / S_GRID);

        unsigned long long key = keybuf[cid];
        int m = (int)(0xFFFFFFFFu - (unsigned)(key & 0xFFFFFFFFull));
        float best_iou = __uint_as_float((unsigned)(key >> 32));
        const float* t = tgt + (size_t)m * 5;
        float cx = t[1], cy = t[2], gw = t[3], gh = t[4];

        // recompute best_j exactly as kernel 1 did
        float dx0 = (a.x + colf) * CELLSZ, dy0 = (a.y + rowf) * CELLSZ;
        float iou0 = iou_fn(dx0, dy0, a.z, a.w, cx, cy, gw, gh);
        float dx1 = (bq.y + colf) * CELLSZ, dy1 = (bq.z + rowf) * CELLSZ;
        float iou1 = iou_fn(dx1, dy1, bq.w, c.x, cx, cy, gw, gh);
        int bj = (iou0 >= iou1) ? 0 : 1;        // argmax, first max wins

        float rx = bj ? bq.y : a.x;
        float ry = bj ? bq.z : a.y;
        float rw = bj ? bq.w : a.z;
        float rh = bj ? c.x  : a.w;
        float rconf = bj ? c.y : bq.x;
        float oconf = bj ? bq.x : c.y;

        // coord loss (CIoU) on abs boxes; |w|,|h| for pred
        float pax = (rx + colf) * CELLSZ, pay = (ry + rowf) * CELLSZ;
        float paw = fabsf(rw), pah = fabsf(rh);
        float cx_rel = cx * (float)S_GRID - colf;
        float cy_rel = cy * (float)S_GRID - rowf;
        float gax = (cx_rel + colf) * CELLSZ;
        float gay = (cy_rel + rowf) * CELLSZ;
        float lcoord = ciou_fn(pax, pay, paw, pah, gax, gay, gw, gh);

        float dobj = rconf - best_iou;

        float cls_logit[10];
        cls_logit[0] = c.z; cls_logit[1] = c.w;
        cls_logit[2] = d.x; cls_logit[3] = d.y; cls_logit[4] = d.z; cls_logit[5] = d.w;
        cls_logit[6] = e.x; cls_logit[7] = e.y; cls_logit[8] = e.z; cls_logit[9] = e.w;
        float lcls = 0.f;
#pragma unroll
        for (int k = 0; k < 10; ++k) {
            float tk = (mask >> k) & 1u ? 1.f : 0.f;
            lcls += focal_fn(cls_logit[k], tk);
        }

        acc = 5.f * lcoord + dobj * dobj + 0.1f * (oconf * oconf) + lcls;
    }

    // deterministic block reduction: wave64 shuffle + LDS across 4 waves
    for (int off = 32; off > 0; off >>= 1) acc += __shfl_down(acc, off);
    __shared__ float sred[BLK / 64];
    int lane = threadIdx.x & 63, wid = threadIdx.x >> 6;
    if (lane == 0) sred[wid] = acc;
    __syncthreads();
    if (threadIdx.x == 0) {
        float s = 0.f;
#pragma unroll
        for (int w = 0; w < BLK / 64; ++w) s += sred[w];
        partial[blockIdx.x] = s;
    }
}

// ---------- kernel 3: final reduction ----------

__global__ void reduce_kernel(const float* __restrict__ partial, float* __restrict__ out) {
    float acc = 0.f;
    for (int i = threadIdx.x; i < NBLK2; i += blockDim.x) acc += partial[i];
    for (int off = 32; off > 0; off >>= 1) acc += __shfl_down(acc, off);
    __shared__ float sred[BLK / 64];
    int lane = threadIdx.x & 63, wid = threadIdx.x >> 6;
    if (lane == 0) sred[wid] = acc;
    __syncthreads();
    if (threadIdx.x == 0) {
        float s = 0.f;
#pragma unroll
        for (int w = 0; w < BLK / 64; ++w) s += sred[w];
        out[0] = s / (float)BATCH_N;
    }
}

// ---------- launcher ----------

extern "C" void kernel_launch(void* const* d_in, const int* in_sizes, int n_in,
                              void* d_out, int out_size, void* d_ws, size_t ws_size,
                              hipStream_t stream) {
    const float* pred = (const float*)d_in[0];
    const float* tgt  = (const float*)d_in[1];

    // workspace layout
    unsigned long long* keybuf  = (unsigned long long*)d_ws;                 // 8B * NCELLS
    unsigned int*       clsmask = (unsigned int*)(keybuf + NCELLS);          // 4B * NCELLS
    float*              partial = (float*)(clsmask + NCELLS);                // 4B * NBLK2

    size_t zero_bytes = (size_t)NCELLS * 12;   // keybuf + clsmask must start at 0
    hipMemsetAsync(d_ws, 0, zero_bytes, stream);

    assign_kernel<<<(BATCH_N * NBOX + BLK - 1) / BLK, BLK, 0, stream>>>(
        pred, tgt, keybuf, clsmask);
    loss_kernel<<<NBLK2, BLK, 0, stream>>>(pred, tgt, keybuf, clsmask, partial);
    reduce_kernel<<<1, BLK, 0, stream>>>(partial, (float*)d_out);
}